// Round 15
// baseline (713.401 us; speedup 1.0000x reference)
//
#include <hip/hip_runtime.h>
#include <hip/hip_bf16.h>

#define NB   8
#define SS   2048
#define DD   1024
#define DFFN 4096
#define MTOT (NB*SS)   // 16384

typedef unsigned short u16;
typedef __attribute__((ext_vector_type(4))) float f32x4;
typedef __attribute__((ext_vector_type(8))) short bf16x8;
typedef __attribute__((ext_vector_type(4))) int i32x4;
typedef __attribute__((ext_vector_type(4))) unsigned short u16x4;
typedef __attribute__((ext_vector_type(8))) unsigned short u16x8;

__device__ __forceinline__ u16 f2bf(float f) {
  union { float f; unsigned u; } c; c.f = f;
  unsigned r = c.u + 0x7FFFu + ((c.u >> 16) & 1u);
  return (u16)(r >> 16);
}

__device__ __forceinline__ void gload16(const void* g, void* l) {
  __builtin_amdgcn_global_load_lds(
      (const __attribute__((address_space(1))) void*)(unsigned long long)g,
      (__attribute__((address_space(3))) void*)(unsigned)(unsigned long long)l,
      16, 0, 0);
}

__device__ __forceinline__ bf16x8 dsr128(unsigned addr) {
  i32x4 r;
  asm volatile("ds_read_b128 %0, %1" : "=v"(r) : "v"(addr));
  return __builtin_bit_cast(bf16x8, r);
}

// ---------------------------------------------------------------------------
// R5/R11-proven 128x128 GEMM-BT (QKV / scores / PV): unchanged control.
// ---------------------------------------------------------------------------
template<int EBIAS, int EGELU, int ESCALE, int EROWSCALE, int OUTMODE, int CSKIP, int CK>
__global__ __launch_bounds__(256, 4)
void gemm128(const u16* __restrict__ A, const u16* __restrict__ B,
             const float* __restrict__ bias0, const float* __restrict__ bias1,
             const float* __restrict__ bias2, const float* __restrict__ rowscale,
             void* __restrict__ C0, void* __restrict__ C1, void* __restrict__ C2,
             int K, int lda, int ldb, int ldc, float scale,
             long long sA, long long sB, long long sC, int sRS)
{
  __shared__ __align__(1024) u16 smem[16384];   // 32 KB

  const int nwg = gridDim.x * gridDim.y;
  const int orig = blockIdx.y * gridDim.x + blockIdx.x;
  const int q = nwg >> 3, r = nwg & 7;
  const int xcd = orig & 7, pos0 = orig >> 3;
  const int wg = (xcd < r ? xcd * (q + 1) : r * (q + 1) + (xcd - r) * q) + pos0;
  const int bx = wg % gridDim.x, by = wg / gridDim.x;
  const int row0 = by * 128, col0 = bx * 128;
  if (CSKIP && col0 > row0 + 127) return;

  const int z = blockIdx.z;
  A += (size_t)z * sA;
  B += (size_t)z * sB;

  int nkt = K >> 5;
  if (CK) { int lim = (row0 + 128) >> 5; if (lim < nkt) nkt = lim; }

  const int tid  = threadIdx.x;
  const int wid  = tid >> 6;
  const int lane = tid & 63;
  const int wr = wid >> 1, wc = wid & 1;

  const int srow = wid * 16 + (lane >> 2);
  const int sunit = (lane & 3) ^ ((lane >> 3) & 3);
  const char* gA = (const char*)A + ((size_t)(row0 + srow) * lda + sunit * 8) * 2;
  const char* gB = (const char*)B + ((size_t)(col0 + srow) * ldb + sunit * 8) * 2;
  const size_t ldab = (size_t)64 * lda * 2;
  const size_t ldbb = (size_t)64 * ldb * 2;

  #define STG(t2) { char* lb = (char*)smem + ((t2) & 1) * 16384; size_t kb = (size_t)(t2) * 64; \
      gload16(gA + kb,        lb + wid * 1024);                                                 \
      gload16(gA + kb + ldab, lb + 4096 + wid * 1024);                                          \
      gload16(gB + kb,        lb + 8192 + wid * 1024);                                          \
      gload16(gB + kb + ldbb, lb + 8192 + 4096 + wid * 1024); }

  const int fr = lane & 15;
  const int ks16 = ((lane >> 4) & 3) * 16;
  const int xm = ((lane >> 1) & 3) << 4;
  const unsigned sbase = (unsigned)(unsigned long long)(void*)smem;

  f32x4 acc[4][4] = {};

  STG(0);
  asm volatile("s_waitcnt vmcnt(0)");
  asm volatile("s_barrier" ::: "memory");

  for (int t = 0; t < nkt; ++t) {
    if (t + 1 < nkt) STG(t + 1);
    const unsigned cb = sbase + (t & 1) * 16384;
    bf16x8 af[4], bf[4];
#pragma unroll
    for (int m = 0; m < 4; ++m)
      af[m] = dsr128(cb + (((wr * 64 + m * 16 + fr) * 64 + ks16) ^ xm));
#pragma unroll
    for (int n = 0; n < 4; ++n)
      bf[n] = dsr128(cb + ((8192 + (wc * 64 + n * 16 + fr) * 64 + ks16) ^ xm));
    asm volatile("s_waitcnt lgkmcnt(0)");
    __builtin_amdgcn_sched_barrier(0);
    __builtin_amdgcn_s_setprio(1);
#pragma unroll
    for (int m = 0; m < 4; ++m)
#pragma unroll
      for (int n = 0; n < 4; ++n)
        acc[m][n] = __builtin_amdgcn_mfma_f32_16x16x32_bf16(af[m], bf[n], acc[m][n], 0, 0, 0);
    __builtin_amdgcn_s_setprio(0);
    asm volatile("s_waitcnt vmcnt(0)");
    asm volatile("s_barrier" ::: "memory");
  }
  #undef STG

  char* sm = (char*)smem;
  const int r4 = (lane >> 4) * 4;
  const int sel  = (OUTMODE == 3) ? (col0 >> 10) : 0;
  const int oc0  = (OUTMODE == 3) ? (col0 & 1023) : col0;
  const float* bias = (OUTMODE == 3) ? (sel == 0 ? bias0 : sel == 1 ? bias1 : bias2)
                                     : bias0;

  if (OUTMODE == 1) {
#pragma unroll
    for (int p = 0; p < 2; ++p) {
      if (wc == p) {
#pragma unroll
        for (int n = 0; n < 4; ++n) {
          const int col = oc0 + wc * 64 + n * 16 + fr;
          const int pb = (n * 16 + fr) * 4;
          float bia = EBIAS ? bias[col] : 0.0f;
#pragma unroll
          for (int m = 0; m < 4; ++m) {
#pragma unroll
            for (int j = 0; j < 4; ++j) {
              const int line = wr * 64 + m * 16 + r4 + j;
              float xv = acc[m][n][j];
              if (EBIAS)     xv += bia;
              if (ESCALE)    xv *= scale;
              if (EROWSCALE) xv *= rowscale[z * sRS + row0 + line];
              if (EGELU)     xv = 0.5f * xv * (1.0f + erff(xv * 0.70710678118f));
              *(float*)(sm + ((line * 256 + pb) ^ ((line & 7) << 4))) = xv;
            }
          }
        }
      }
      __syncthreads();
      float* Cb = (float*)C0 + (size_t)z * sC;
#pragma unroll
      for (int i = 0; i < 8; ++i) {
        const int o = i * 4096 + tid * 16;
        const int line = o >> 8, ps = o & 255;
        f32x4 v = *(const f32x4*)(sm + ((line * 256 + ps) ^ ((line & 7) << 4)));
        *(f32x4*)((char*)(Cb + (size_t)(row0 + line) * ldc + oc0 + p * 64) + ps) = v;
      }
      __syncthreads();
    }
  } else if (OUTMODE == 3 && sel == 2) {
#pragma unroll
    for (int n = 0; n < 4; ++n) {
      const int line = wc * 64 + n * 16 + fr;
      float bia = EBIAS ? bias[oc0 + line] : 0.0f;
#pragma unroll
      for (int m = 0; m < 4; ++m) {
        const int rb = wr * 64 + m * 16 + r4;
        u16x4 pk;
#pragma unroll
        for (int j = 0; j < 4; ++j) pk[j] = f2bf(acc[m][n][j] + bia);
        *(u16x4*)(sm + ((line * 256 + rb * 2) ^ ((line & 7) << 4))) = pk;
      }
    }
    __syncthreads();
    u16* Cb = (u16*)C2 + (size_t)(row0 >> 11) * (DD * SS) + (row0 & (SS - 1));
#pragma unroll
    for (int i = 0; i < 8; ++i) {
      const int o = i * 4096 + tid * 16;
      const int line = o >> 8, ps = o & 255;
      f32x4 v = *(const f32x4*)(sm + ((line * 256 + ps) ^ ((line & 7) << 4)));
      *(f32x4*)((char*)(Cb + (size_t)(oc0 + line) * SS) + ps) = v;
    }
  } else {
#pragma unroll
    for (int n = 0; n < 4; ++n) {
      const int col = oc0 + wc * 64 + n * 16 + fr;
      const int pc = (wc * 64 + n * 16 + fr) * 2;
      float bia = EBIAS ? bias[col] : 0.0f;
#pragma unroll
      for (int m = 0; m < 4; ++m) {
#pragma unroll
        for (int j = 0; j < 4; ++j) {
          const int line = wr * 64 + m * 16 + r4 + j;
          float xv = acc[m][n][j];
          if (EBIAS)     xv += bia;
          if (ESCALE)    xv *= scale;
          if (EROWSCALE) xv *= rowscale[z * sRS + row0 + line];
          if (EGELU)     xv = 0.5f * xv * (1.0f + erff(xv * 0.70710678118f));
          u16 u;
          if (OUTMODE == 2) { union { u16 s; _Float16 h; } cu; cu.h = (_Float16)xv; u = cu.s; }
          else u = f2bf(xv);
          *(u16*)(sm + ((line * 256 + pc) ^ ((line & 7) << 4))) = u;
        }
      }
    }
    __syncthreads();
    u16* Cb = (u16*)(OUTMODE == 3 ? (sel ? C1 : C0) : C0) + (size_t)z * sC + oc0;
#pragma unroll
    for (int i = 0; i < 8; ++i) {
      const int o = i * 4096 + tid * 16;
      const int line = o >> 8, ps = o & 255;
      f32x4 v = *(const f32x4*)(sm + ((line * 256 + ps) ^ ((line & 7) << 4)));
      *(f32x4*)((char*)(Cb + (size_t)(row0 + line) * ldc) + ps) = v;
    }
  }
}

// ---------------------------------------------------------------------------
// 256x256 GEMM-BT, m201-shape phases. 512 thr = 8 waves (2x4), per-wave
// 128x64 out (acc 8x4). BK=64, 2 x 64KB LDS buffers. Per K-tile, 4 phases:
// {reads for THIS phase's 16 MFMAs (p0 also reads B); stage 2 slots of tile
// T+1; [vmcnt(4)@p1 / vmcnt(2)@p3]; barrier; lgkmcnt(0)+sched_barrier;
// setprio(1); 16 MFMA; setprio(0); barrier}. Stage order per tile T:
// p0:B12(T+1) p1:B34(T+1) p2:A13(T+1) p3:A24(T+1). FIFO: p1's vmcnt(4)
// retires A24(T) (needed by p2 reads); p3's vmcnt(2) retires B+A13(T+1)
// (needed by p0(T+1) reads). Single av/bb operand set (~200 VGPR, no spill).
// ---------------------------------------------------------------------------
template<int EGELU, int OUTF32>
__global__ __launch_bounds__(512, 2)
void gemm256ph(const u16* __restrict__ A, const u16* __restrict__ B,
               const float* __restrict__ bias, void* __restrict__ C,
               int K, int lda, int ldb, int ldc)
{
  __shared__ __align__(1024) u16 smem[65536];   // 128 KB

  const int nwg = gridDim.x * gridDim.y;
  const int orig = blockIdx.y * gridDim.x + blockIdx.x;
  const int q = nwg >> 3, r = nwg & 7;
  const int xcd = orig & 7, pos0 = orig >> 3;
  const int wg = (xcd < r ? xcd * (q + 1) : r * (q + 1) + (xcd - r) * q) + pos0;
  const int bx = wg % gridDim.x, by = wg / gridDim.x;
  const int row0 = by * 256, col0 = bx * 256;

  const int nkt = K >> 6;                 // K-tiles of 64 (16 or 64, even, >=2)
  const int tid = threadIdx.x, wid = tid >> 6, lane = tid & 63;
  const int wr = wid >> 2, wc = wid & 3;
  const int fr = lane & 15, s = lane >> 4;

  const unsigned aoff0 = wr * 16384 + fr * 128 + (((s)     ^ (fr & 7)) << 4);
  const unsigned aoff1 = wr * 16384 + fr * 128 + (((4 + s) ^ (fr & 7)) << 4);
  const unsigned boff0 = 32768 + wc * 8192 + fr * 128 + (((s)     ^ (fr & 7)) << 4);
  const unsigned boff1 = 32768 + wc * 8192 + fr * 128 + (((4 + s) ^ (fr & 7)) << 4);
  const unsigned sb = (unsigned)(unsigned long long)(void*)smem;

  // staging: lane l -> row +(l>>3), 16B-unit (l&7)^((l>>3)&7) (pre-swizzled)
  const int l8 = lane >> 3;
  const int u8 = (lane & 7) ^ (l8 & 7);
  const char* gAl = (const char*)A + ((size_t)(row0 + wid * 8 + l8) * lda) * 2 + u8 * 16;
  const char* gBl = (const char*)B + ((size_t)(col0 + wid * 8 + l8) * ldb) * 2 + u8 * 16;
  const size_t lda64 = (size_t)64 * lda * 2;
  const size_t ldb64 = (size_t)64 * ldb * 2;

  #define STGA(BUFB, S4, TT) gload16(gAl + (S4) * lda64 + (size_t)(TT) * 128, \
      (char*)smem + (BUFB) + ((S4) * 64 + wid * 8) * 128)
  #define STGB(BUFB, S4, TT) gload16(gBl + (S4) * ldb64 + (size_t)(TT) * 128, \
      (char*)smem + (BUFB) + 32768 + ((S4) * 64 + wid * 8) * 128)

  #define RDA(BUFB, M0) {                                        \
    av[0] = dsr128(sb + (BUFB) + (M0) * 2048 + aoff0);           \
    av[1] = dsr128(sb + (BUFB) + (M0) * 2048 + aoff1);           \
    av[2] = dsr128(sb + (BUFB) + ((M0) + 1) * 2048 + aoff0);     \
    av[3] = dsr128(sb + (BUFB) + ((M0) + 1) * 2048 + aoff1); }
  #define RDB(BUFB) {                                            \
    _Pragma("unroll") for (int n = 0; n < 4; ++n) {              \
      bb[n * 2]     = dsr128(sb + (BUFB) + n * 2048 + boff0);    \
      bb[n * 2 + 1] = dsr128(sb + (BUFB) + n * 2048 + boff1); } }

  f32x4 acc[8][4] = {};
  bf16x8 av[4], bb[8];

  #define MFMA16(P)                                                            \
    __builtin_amdgcn_s_setprio(1);                                             \
    _Pragma("unroll") for (int mm = 0; mm < 2; ++mm)                           \
    _Pragma("unroll") for (int n = 0; n < 4; ++n)                              \
    _Pragma("unroll") for (int h = 0; h < 2; ++h)                              \
      acc[(P) * 2 + mm][n] = __builtin_amdgcn_mfma_f32_16x16x32_bf16(          \
          av[mm * 2 + h], bb[n * 2 + h], acc[(P) * 2 + mm][n], 0, 0, 0);       \
    __builtin_amdgcn_s_setprio(0);

  #define BAR       asm volatile("s_barrier" ::: "memory")
  #define LGK0      asm volatile("s_waitcnt lgkmcnt(0)" ::: "memory"); \
                    __builtin_amdgcn_sched_barrier(0)

  // prologue: stage ALL of tile 0, drain, barrier
  STGB(0, 0, 0); STGB(0, 1, 0); STGB(0, 2, 0); STGB(0, 3, 0);
  STGA(0, 0, 0); STGA(0, 1, 0); STGA(0, 2, 0); STGA(0, 3, 0);
  asm volatile("s_waitcnt vmcnt(0)" ::: "memory");
  BAR;

  for (int T = 0; T < nkt - 1; ++T) {
    const unsigned cb = (unsigned)(T & 1) * 65536u;
    const unsigned nb = cb ^ 65536u;
    // p0: read B(T)+A m0,1; stage B12(T+1)
    RDB(cb); RDA(cb, 0);
    STGB(nb, 0, T + 1); STGB(nb, 1, T + 1);
    BAR; LGK0; MFMA16(0); BAR;
    // p1: read A m2,3; stage B34(T+1); vmcnt(4) retires A24(T)
    RDA(cb, 2);
    STGB(nb, 2, T + 1); STGB(nb, 3, T + 1);
    asm volatile("s_waitcnt vmcnt(4)" ::: "memory");
    BAR; LGK0; MFMA16(1); BAR;
    // p2: read A m4,5 (slots 1,3 of T); stage A13(T+1)
    RDA(cb, 4);
    STGA(nb, 0, T + 1); STGA(nb, 2, T + 1);
    BAR; LGK0; MFMA16(2); BAR;
    // p3: read A m6,7; stage A24(T+1); vmcnt(2) retires B+A13(T+1)
    RDA(cb, 6);
    STGA(nb, 1, T + 1); STGA(nb, 3, T + 1);
    asm volatile("s_waitcnt vmcnt(2)" ::: "memory");
    BAR; LGK0; MFMA16(3); BAR;
  }
  // last tile (T = nkt-1): no stages; vmcnt(0)@p1 drains A24(last)
  {
    const unsigned cb = (unsigned)((nkt - 1) & 1) * 65536u;
    RDB(cb); RDA(cb, 0);
    BAR; LGK0; MFMA16(0); BAR;
    RDA(cb, 2);
    asm volatile("s_waitcnt vmcnt(0)" ::: "memory");
    BAR; LGK0; MFMA16(1); BAR;
    RDA(cb, 4);
    BAR; LGK0; MFMA16(2); BAR;
    RDA(cb, 6);
    BAR; LGK0; MFMA16(3); BAR;
  }
  #undef STGA
  #undef STGB
  #undef RDA
  #undef RDB
  #undef MFMA16
  #undef BAR
  #undef LGK0

  __syncthreads();

  // ---- epilogue via LDS (full-line stores) ----
  char* sm = (char*)smem;
  const int r4 = s * 4;

  if (OUTF32) {
#pragma unroll
    for (int p = 0; p < 2; ++p) {
      if ((wc >> 1) == p) {
#pragma unroll
        for (int n = 0; n < 4; ++n) {
          const int col = col0 + wc * 64 + n * 16 + fr;
          const int pb = ((wc & 1) * 64 + n * 16 + fr) * 4;
          const float bia = bias[col];
#pragma unroll
          for (int m = 0; m < 8; ++m) {
#pragma unroll
            for (int j = 0; j < 4; ++j) {
              const int line = wr * 128 + m * 16 + r4 + j;
              float xv = acc[m][n][j] + bia;
              if (EGELU) xv = 0.5f * xv * (1.0f + erff(xv * 0.70710678118f));
              *(float*)(sm + ((line * 512 + pb) ^ ((line & 7) << 4))) = xv;
            }
          }
        }
      }
      __syncthreads();
#pragma unroll
      for (int i = 0; i < 16; ++i) {
        const int o = i * 8192 + tid * 16;
        const int line = o >> 9, ps = o & 511;
        f32x4 v = *(const f32x4*)(sm + ((line * 512 + ps) ^ ((line & 7) << 4)));
        *(f32x4*)((char*)((float*)C + (size_t)(row0 + line) * ldc + col0 + p * 128) + ps) = v;
      }
      __syncthreads();
    }
  } else {
#pragma unroll
    for (int n = 0; n < 4; ++n) {
      const int col = col0 + wc * 64 + n * 16 + fr;
      const int pc = (wc * 64 + n * 16 + fr) * 2;
      const float bia = bias[col];
#pragma unroll
      for (int m = 0; m < 8; ++m) {
#pragma unroll
        for (int j = 0; j < 4; ++j) {
          const int line = wr * 128 + m * 16 + r4 + j;
          float xv = acc[m][n][j] + bia;
          if (EGELU) xv = 0.5f * xv * (1.0f + erff(xv * 0.70710678118f));
          *(u16*)(sm + ((line * 512 + pc) ^ ((line & 7) << 4))) = f2bf(xv);
        }
      }
    }
    __syncthreads();
#pragma unroll
    for (int i = 0; i < 16; ++i) {
      const int o = i * 8192 + tid * 16;
      const int line = o >> 9, ps = o & 511;
      f32x4 v = *(const f32x4*)(sm + ((line * 512 + ps) ^ ((line & 7) << 4)));
      *(f32x4*)((char*)((u16*)C + (size_t)(row0 + line) * ldc + col0) + ps) = v;
    }
  }
}

// single fused f32->bf16 convert: x -> out_x, weights -> out_w (contiguous)
__global__ __launch_bounds__(256) void cvt_all_k(
    const float* __restrict__ x,  const float* __restrict__ wq,
    const float* __restrict__ wk, const float* __restrict__ wv,
    const float* __restrict__ w1, const float* __restrict__ w2,
    u16* __restrict__ out_x, u16* __restrict__ out_w)
{
  const int i = blockIdx.x * 256 + threadIdx.x;   // float4 index
  const float* src; int off; u16* dst; int dofs;
  if (i < 4194304)      { src = x;  off = i;           dst = out_x; dofs = i; }
  else if (i < 4456448) { src = wq; off = i - 4194304; dst = out_w; dofs = i - 4194304; }
  else if (i < 4718592) { src = wk; off = i - 4456448; dst = out_w; dofs = i - 4194304; }
  else if (i < 4980736) { src = wv; off = i - 4718592; dst = out_w; dofs = i - 4194304; }
  else if (i < 6029312) { src = w1; off = i - 4980736; dst = out_w; dofs = i - 4194304; }
  else                  { src = w2; off = i - 6029312; dst = out_w; dofs = i - 4194304; }
  float4 v = ((const float4*)src)[off];
  u16x4 o;
  o.x = f2bf(v.x); o.y = f2bf(v.y); o.z = f2bf(v.z); o.w = f2bf(v.w);
  ((u16x4*)dst)[dofs] = o;
}

// batched row softmax over f16 scores -> unnormalized bf16 P + 1/sum
__global__ __launch_bounds__(256) void softmax_k(u16* __restrict__ sc, float* __restrict__ rinv, int rows0) {
  const int widx = blockIdx.x * 4 + (threadIdx.x >> 6);
  const int lane = threadIdx.x & 63;
  u16* row = sc + (size_t)widx * SS;
  const int L = (widx & (SS - 1)) + 1;
  float mx = -1e30f;
  for (int k = 0; k < 4; ++k) {
    const int j0 = k * 512 + lane * 8;
    if (j0 < L) {
      u16x8 v = *(const u16x8*)(row + j0);
      int lim = L - j0; if (lim > 8) lim = 8;
#pragma unroll
      for (int e = 0; e < 8; ++e) {
        if (e < lim) { union { u16 u; _Float16 h; } c; c.u = v[e]; mx = fmaxf(mx, (float)c.h); }
      }
    }
  }
#pragma unroll
  for (int o = 32; o >= 1; o >>= 1) mx = fmaxf(mx, __shfl_xor(mx, o));
  float sacc = 0.0f;
  for (int k = 0; k < 4; ++k) {
    const int j0 = k * 512 + lane * 8;
    u16x8 v = *(const u16x8*)(row + j0);
    u16x8 w;
#pragma unroll
    for (int e = 0; e < 8; ++e) {
      const int j = j0 + e;
      float ev = 0.0f;
      if (j < L) { union { u16 u; _Float16 h; } c; c.u = v[e]; ev = __expf((float)c.h - mx); sacc += ev; }
      w[e] = f2bf(ev);
    }
    *(u16x8*)(row + j0) = w;
  }
#pragma unroll
  for (int o = 32; o >= 1; o >>= 1) sacc += __shfl_xor(sacc, o);
  if (lane == 0) rinv[rows0 + widx] = 1.0f / sacc;
}

extern "C" void kernel_launch(void* const* d_in, const int* in_sizes, int n_in,
                              void* d_out, int out_size, void* d_ws, size_t ws_size,
                              hipStream_t stream) {
  const float* x  = (const float*)d_in[0];
  const float* Wq = (const float*)d_in[1];
  const float* bq = (const float*)d_in[2];
  const float* Wk = (const float*)d_in[3];
  const float* bk = (const float*)d_in[4];
  const float* Wv = (const float*)d_in[5];
  const float* bv = (const float*)d_in[6];
  const float* W1 = (const float*)d_in[7];
  const float* b1 = (const float*)d_in[8];
  const float* W2 = (const float*)d_in[9];
  const float* b2 = (const float*)d_in[10];

  char* ws = (char*)d_ws;
  u16*  Qb   = (u16*)(ws);                          // 32 MB; att overwrites
  u16*  Kb   = (u16*)(ws + 33554432);               // 32 MB; h overwrites
  u16*  Vtb  = (u16*)(ws + 67108864);               // 32 MB
  u16*  big  = (u16*)(ws + 100663296);              // scores/P 64 MB; xb first
  float* rinv = (float*)(ws + 167772160);           // 64 KB
  u16*  Wcat = (u16*)(ws + 167772160 + 65536);      // 6 MB
  u16*  W1b  = Wcat + 3 * DD * DD;                  // 8 MB
  u16*  W2b  = W1b + DFFN * DD;                     // 8 MB
  u16*  xb   = big;
  u16*  att  = Qb;
  u16*  h    = Kb;                                  // 128 MB over Kb|Vtb|big

  cvt_all_k<<<27648, 256, 0, stream>>>(x, Wq, Wk, Wv, W1, W2, xb, Wcat);

  // fused QKV (control, gemm128)
  gemm128<1,0,0,0,3,0,0><<<dim3(3 * DD / 128, MTOT / 128), 256, 0, stream>>>(
      xb, Wcat, bq, bk, bv, nullptr, (void*)Qb, (void*)Kb, (void*)Vtb,
      DD, DD, DD, DD, 0.f, 0, 0, 0, 0);

  // attention, all batches
  gemm128<0,0,1,0,2,1,0><<<dim3(SS/128, SS/128, NB), 256, 0, stream>>>(
      Qb, Kb, nullptr, nullptr, nullptr, nullptr, (void*)big, nullptr, nullptr,
      DD, DD, DD, SS, 0.03125f,
      (long long)SS * DD, (long long)SS * DD, (long long)SS * SS, 0);
  softmax_k<<<NB * SS / 4, 256, 0, stream>>>(big, rinv, 0);
  gemm128<0,0,0,1,0,0,1><<<dim3(DD/128, SS/128, NB), 256, 0, stream>>>(
      big, Vtb, nullptr, nullptr, nullptr, rinv,
      (void*)att, nullptr, nullptr,
      SS, SS, SS, DD, 0.f,
      (long long)SS * SS, (long long)DD * SS, (long long)SS * DD, SS);

  // MLP full-M via the rebuilt 256^2 phase kernel
  gemm256ph<1,0><<<dim3(DFFN/256, MTOT/256), 512, 0, stream>>>(
      att, W1b, b1, (void*)h, DD, DD, DD, DFFN);
  gemm256ph<0,1><<<dim3(DD/256, MTOT/256), 512, 0, stream>>>(
      h, W2b, b2, (void*)d_out, DFFN, DFFN, DFFN, DD);
}

// Round 16
// 686.068 us; speedup vs baseline: 1.0398x; 1.0398x over previous
//
#include <hip/hip_runtime.h>
#include <hip/hip_bf16.h>

#define NB   8
#define SS   2048
#define DD   1024
#define DFFN 4096
#define MTOT (NB*SS)   // 16384

typedef unsigned short u16;
typedef __attribute__((ext_vector_type(4))) float f32x4;
typedef __attribute__((ext_vector_type(8))) short bf16x8;
typedef __attribute__((ext_vector_type(4))) int i32x4;
typedef __attribute__((ext_vector_type(4))) unsigned short u16x4;
typedef __attribute__((ext_vector_type(8))) unsigned short u16x8;

__device__ __forceinline__ u16 f2bf(float f) {
  union { float f; unsigned u; } c; c.f = f;
  unsigned r = c.u + 0x7FFFu + ((c.u >> 16) & 1u);
  return (u16)(r >> 16);
}

__device__ __forceinline__ void gload16(const void* g, void* l) {
  __builtin_amdgcn_global_load_lds(
      (const __attribute__((address_space(1))) void*)(unsigned long long)g,
      (__attribute__((address_space(3))) void*)(unsigned)(unsigned long long)l,
      16, 0, 0);
}

// opaque ds_read_b128 (manual lgkmcnt/vmcnt accounting)
__device__ __forceinline__ bf16x8 dsr128(unsigned addr) {
  i32x4 r;
  asm volatile("ds_read_b128 %0, %1" : "=v"(r) : "v"(addr));
  return __builtin_bit_cast(bf16x8, r);
}

// ---------------------------------------------------------------------------
// R5/R11-proven 128x128 GEMM-BT: 4 waves (2x2), per-wave 64x64, BK=32,
// 2-buffer LDS ring (32KB), MINW=4 (124 regs fits; 5 proven bad R10).
// NEW (R16): supertile block-order — within the XCD-swizzled linear order,
// walk 4-column super-stripes so each XCD chunk keeps 4 B-panels (1MB)
// resident in its 4MB L2 and 4 consecutive blocks share one A-row-panel.
// Attacks MLP1's 322MB / QKV's 190MB FETCH (ideal ~40MB).
// OUTMODE: 0=bf16, 1=f32, 2=f16, 3=QKV fused (Q,K bf16 rows + V transposed).
// ---------------------------------------------------------------------------
template<int EBIAS, int EGELU, int ESCALE, int EROWSCALE, int OUTMODE, int CSKIP, int CK>
__global__ __launch_bounds__(256, 4)
void gemm128(const u16* __restrict__ A, const u16* __restrict__ B,
             const float* __restrict__ bias0, const float* __restrict__ bias1,
             const float* __restrict__ bias2, const float* __restrict__ rowscale,
             void* __restrict__ C0, void* __restrict__ C1, void* __restrict__ C2,
             int K, int lda, int ldb, int ldc, float scale,
             long long sA, long long sB, long long sC, int sRS)
{
  __shared__ __align__(1024) u16 smem[16384];   // 32 KB

  const int gx = gridDim.x, gy = gridDim.y;
  const int nwg = gx * gy;
  const int orig = blockIdx.y * gx + blockIdx.x;
  const int q = nwg >> 3, r = nwg & 7;
  const int xcd = orig & 7, pos0 = orig >> 3;
  const int wg = (xcd < r ? xcd * (q + 1) : r * (q + 1) + (xcd - r) * q) + pos0;
  int bx, by;
  if ((gx & 3) == 0) {               // supertile: 4-col stripes (bijective)
    const int rr = wg % (gy << 2);
    bx = (wg / (gy << 2)) * 4 + (rr & 3);
    by = rr >> 2;
  } else {
    bx = wg % gx; by = wg / gx;
  }
  const int row0 = by * 128, col0 = bx * 128;
  if (CSKIP && col0 > row0 + 127) return;

  const int z = blockIdx.z;
  A += (size_t)z * sA;
  B += (size_t)z * sB;

  int nkt = K >> 5;
  if (CK) { int lim = (row0 + 128) >> 5; if (lim < nkt) nkt = lim; }

  const int tid  = threadIdx.x;
  const int wid  = tid >> 6;
  const int lane = tid & 63;
  const int wr = wid >> 1, wc = wid & 1;

  const int srow = wid * 16 + (lane >> 2);
  const int sunit = (lane & 3) ^ ((lane >> 3) & 3);
  const char* gA = (const char*)A + ((size_t)(row0 + srow) * lda + sunit * 8) * 2;
  const char* gB = (const char*)B + ((size_t)(col0 + srow) * ldb + sunit * 8) * 2;
  const size_t ldab = (size_t)64 * lda * 2;
  const size_t ldbb = (size_t)64 * ldb * 2;

  #define STG(t2) { char* lb = (char*)smem + ((t2) & 1) * 16384; size_t kb = (size_t)(t2) * 64; \
      gload16(gA + kb,        lb + wid * 1024);                                                 \
      gload16(gA + kb + ldab, lb + 4096 + wid * 1024);                                          \
      gload16(gB + kb,        lb + 8192 + wid * 1024);                                          \
      gload16(gB + kb + ldbb, lb + 8192 + 4096 + wid * 1024); }

  const int fr = lane & 15;
  const int ks16 = ((lane >> 4) & 3) * 16;
  const int xm = ((lane >> 1) & 3) << 4;
  const unsigned sbase = (unsigned)(unsigned long long)(void*)smem;

  f32x4 acc[4][4] = {};

  STG(0);
  asm volatile("s_waitcnt vmcnt(0)");
  asm volatile("s_barrier" ::: "memory");

  for (int t = 0; t < nkt; ++t) {
    if (t + 1 < nkt) STG(t + 1);
    const unsigned cb = sbase + (t & 1) * 16384;
    bf16x8 af[4], bf[4];
#pragma unroll
    for (int m = 0; m < 4; ++m)
      af[m] = dsr128(cb + (((wr * 64 + m * 16 + fr) * 64 + ks16) ^ xm));
#pragma unroll
    for (int n = 0; n < 4; ++n)
      bf[n] = dsr128(cb + ((8192 + (wc * 64 + n * 16 + fr) * 64 + ks16) ^ xm));
    asm volatile("s_waitcnt lgkmcnt(0)");
    __builtin_amdgcn_sched_barrier(0);
    __builtin_amdgcn_s_setprio(1);
#pragma unroll
    for (int m = 0; m < 4; ++m)
#pragma unroll
      for (int n = 0; n < 4; ++n)
        acc[m][n] = __builtin_amdgcn_mfma_f32_16x16x32_bf16(af[m], bf[n], acc[m][n], 0, 0, 0);
    __builtin_amdgcn_s_setprio(0);
    asm volatile("s_waitcnt vmcnt(0)");
    asm volatile("s_barrier" ::: "memory");
  }
  #undef STG

  char* sm = (char*)smem;
  const int r4 = (lane >> 4) * 4;
  const int sel  = (OUTMODE == 3) ? (col0 >> 10) : 0;
  const int oc0  = (OUTMODE == 3) ? (col0 & 1023) : col0;
  const float* bias = (OUTMODE == 3) ? (sel == 0 ? bias0 : sel == 1 ? bias1 : bias2)
                                     : bias0;

  if (OUTMODE == 1) {
#pragma unroll
    for (int p = 0; p < 2; ++p) {
      if (wc == p) {
#pragma unroll
        for (int n = 0; n < 4; ++n) {
          const int col = oc0 + wc * 64 + n * 16 + fr;
          const int pb = (n * 16 + fr) * 4;
          float bia = EBIAS ? bias[col] : 0.0f;
#pragma unroll
          for (int m = 0; m < 4; ++m) {
#pragma unroll
            for (int j = 0; j < 4; ++j) {
              const int line = wr * 64 + m * 16 + r4 + j;
              float xv = acc[m][n][j];
              if (EBIAS)     xv += bia;
              if (ESCALE)    xv *= scale;
              if (EROWSCALE) xv *= rowscale[z * sRS + row0 + line];
              if (EGELU)     xv = 0.5f * xv * (1.0f + erff(xv * 0.70710678118f));
              *(float*)(sm + ((line * 256 + pb) ^ ((line & 7) << 4))) = xv;
            }
          }
        }
      }
      __syncthreads();
      float* Cb = (float*)C0 + (size_t)z * sC;
#pragma unroll
      for (int i = 0; i < 8; ++i) {
        const int o = i * 4096 + tid * 16;
        const int line = o >> 8, ps = o & 255;
        f32x4 v = *(const f32x4*)(sm + ((line * 256 + ps) ^ ((line & 7) << 4)));
        *(f32x4*)((char*)(Cb + (size_t)(row0 + line) * ldc + oc0 + p * 64) + ps) = v;
      }
      __syncthreads();
    }
  } else if (OUTMODE == 3 && sel == 2) {
#pragma unroll
    for (int n = 0; n < 4; ++n) {
      const int line = wc * 64 + n * 16 + fr;
      float bia = EBIAS ? bias[oc0 + line] : 0.0f;
#pragma unroll
      for (int m = 0; m < 4; ++m) {
        const int rb = wr * 64 + m * 16 + r4;
        u16x4 pk;
#pragma unroll
        for (int j = 0; j < 4; ++j) pk[j] = f2bf(acc[m][n][j] + bia);
        *(u16x4*)(sm + ((line * 256 + rb * 2) ^ ((line & 7) << 4))) = pk;
      }
    }
    __syncthreads();
    u16* Cb = (u16*)C2 + (size_t)(row0 >> 11) * (DD * SS) + (row0 & (SS - 1));
#pragma unroll
    for (int i = 0; i < 8; ++i) {
      const int o = i * 4096 + tid * 16;
      const int line = o >> 8, ps = o & 255;
      f32x4 v = *(const f32x4*)(sm + ((line * 256 + ps) ^ ((line & 7) << 4)));
      *(f32x4*)((char*)(Cb + (size_t)(oc0 + line) * SS) + ps) = v;
    }
  } else {
#pragma unroll
    for (int n = 0; n < 4; ++n) {
      const int col = oc0 + wc * 64 + n * 16 + fr;
      const int pc = (wc * 64 + n * 16 + fr) * 2;
      float bia = EBIAS ? bias[col] : 0.0f;
#pragma unroll
      for (int m = 0; m < 4; ++m) {
#pragma unroll
        for (int j = 0; j < 4; ++j) {
          const int line = wr * 64 + m * 16 + r4 + j;
          float xv = acc[m][n][j];
          if (EBIAS)     xv += bia;
          if (ESCALE)    xv *= scale;
          if (EROWSCALE) xv *= rowscale[z * sRS + row0 + line];
          if (EGELU)     xv = 0.5f * xv * (1.0f + erff(xv * 0.70710678118f));
          u16 u;
          if (OUTMODE == 2) { union { u16 s; _Float16 h; } cu; cu.h = (_Float16)xv; u = cu.s; }
          else u = f2bf(xv);
          *(u16*)(sm + ((line * 256 + pc) ^ ((line & 7) << 4))) = u;
        }
      }
    }
    __syncthreads();
    u16* Cb = (u16*)(OUTMODE == 3 ? (sel ? C1 : C0) : C0) + (size_t)z * sC + oc0;
#pragma unroll
    for (int i = 0; i < 8; ++i) {
      const int o = i * 4096 + tid * 16;
      const int line = o >> 8, ps = o & 255;
      f32x4 v = *(const f32x4*)(sm + ((line * 256 + ps) ^ ((line & 7) << 4)));
      *(f32x4*)((char*)(Cb + (size_t)(row0 + line) * ldc) + ps) = v;
    }
  }
}

// single fused f32->bf16 convert: x -> out_x, weights -> out_w (contiguous)
__global__ __launch_bounds__(256) void cvt_all_k(
    const float* __restrict__ x,  const float* __restrict__ wq,
    const float* __restrict__ wk, const float* __restrict__ wv,
    const float* __restrict__ w1, const float* __restrict__ w2,
    u16* __restrict__ out_x, u16* __restrict__ out_w)
{
  const int i = blockIdx.x * 256 + threadIdx.x;   // float4 index
  const float* src; int off; u16* dst; int dofs;
  if (i < 4194304)      { src = x;  off = i;           dst = out_x; dofs = i; }
  else if (i < 4456448) { src = wq; off = i - 4194304; dst = out_w; dofs = i - 4194304; }
  else if (i < 4718592) { src = wk; off = i - 4456448; dst = out_w; dofs = i - 4194304; }
  else if (i < 4980736) { src = wv; off = i - 4718592; dst = out_w; dofs = i - 4194304; }
  else if (i < 6029312) { src = w1; off = i - 4980736; dst = out_w; dofs = i - 4194304; }
  else                  { src = w2; off = i - 6029312; dst = out_w; dofs = i - 4194304; }
  float4 v = ((const float4*)src)[off];
  u16x4 o;
  o.x = f2bf(v.x); o.y = f2bf(v.y); o.z = f2bf(v.z); o.w = f2bf(v.w);
  ((u16x4*)dst)[dofs] = o;
}

// batched row softmax over f16 scores -> unnormalized bf16 P + 1/sum
__global__ __launch_bounds__(256) void softmax_k(u16* __restrict__ sc, float* __restrict__ rinv, int rows0) {
  const int widx = blockIdx.x * 4 + (threadIdx.x >> 6);
  const int lane = threadIdx.x & 63;
  u16* row = sc + (size_t)widx * SS;
  const int L = (widx & (SS - 1)) + 1;
  float mx = -1e30f;
  for (int k = 0; k < 4; ++k) {
    const int j0 = k * 512 + lane * 8;
    if (j0 < L) {
      u16x8 v = *(const u16x8*)(row + j0);
      int lim = L - j0; if (lim > 8) lim = 8;
#pragma unroll
      for (int e = 0; e < 8; ++e) {
        if (e < lim) { union { u16 u; _Float16 h; } c; c.u = v[e]; mx = fmaxf(mx, (float)c.h); }
      }
    }
  }
#pragma unroll
  for (int o = 32; o >= 1; o >>= 1) mx = fmaxf(mx, __shfl_xor(mx, o));
  float sacc = 0.0f;
  for (int k = 0; k < 4; ++k) {
    const int j0 = k * 512 + lane * 8;
    u16x8 v = *(const u16x8*)(row + j0);
    u16x8 w;
#pragma unroll
    for (int e = 0; e < 8; ++e) {
      const int j = j0 + e;
      float ev = 0.0f;
      if (j < L) { union { u16 u; _Float16 h; } c; c.u = v[e]; ev = __expf((float)c.h - mx); sacc += ev; }
      w[e] = f2bf(ev);
    }
    *(u16x8*)(row + j0) = w;
  }
#pragma unroll
  for (int o = 32; o >= 1; o >>= 1) sacc += __shfl_xor(sacc, o);
  if (lane == 0) rinv[rows0 + widx] = 1.0f / sacc;
}

extern "C" void kernel_launch(void* const* d_in, const int* in_sizes, int n_in,
                              void* d_out, int out_size, void* d_ws, size_t ws_size,
                              hipStream_t stream) {
  const float* x  = (const float*)d_in[0];
  const float* Wq = (const float*)d_in[1];
  const float* bq = (const float*)d_in[2];
  const float* Wk = (const float*)d_in[3];
  const float* bk = (const float*)d_in[4];
  const float* Wv = (const float*)d_in[5];
  const float* bv = (const float*)d_in[6];
  const float* W1 = (const float*)d_in[7];
  const float* b1 = (const float*)d_in[8];
  const float* W2 = (const float*)d_in[9];
  const float* b2 = (const float*)d_in[10];

  char* ws = (char*)d_ws;
  u16*  Qb   = (u16*)(ws);                          // 32 MB; att overwrites
  u16*  Kb   = (u16*)(ws + 33554432);               // 32 MB; h overwrites
  u16*  Vtb  = (u16*)(ws + 67108864);               // 32 MB
  u16*  big  = (u16*)(ws + 100663296);              // scores/P 64 MB; xb first
  float* rinv = (float*)(ws + 167772160);           // 64 KB
  u16*  Wcat = (u16*)(ws + 167772160 + 65536);      // 6 MB
  u16*  W1b  = Wcat + 3 * DD * DD;                  // 8 MB
  u16*  W2b  = W1b + DFFN * DD;                     // 8 MB
  u16*  xb   = big;
  u16*  att  = Qb;
  u16*  h    = Kb;                                  // 128 MB over Kb|Vtb|big

  cvt_all_k<<<27648, 256, 0, stream>>>(x, Wq, Wk, Wv, W1, W2, xb, Wcat);

  // fused QKV projection: N = 3072, grid 24 x 128
  gemm128<1,0,0,0,3,0,0><<<dim3(3 * DD / 128, MTOT / 128), 256, 0, stream>>>(
      xb, Wcat, bq, bk, bv, nullptr, (void*)Qb, (void*)Kb, (void*)Vtb,
      DD, DD, DD, DD, 0.f, 0, 0, 0, 0);

  // attention, all batches
  gemm128<0,0,1,0,2,1,0><<<dim3(SS/128, SS/128, NB), 256, 0, stream>>>(
      Qb, Kb, nullptr, nullptr, nullptr, nullptr, (void*)big, nullptr, nullptr,
      DD, DD, DD, SS, 0.03125f,
      (long long)SS * DD, (long long)SS * DD, (long long)SS * SS, 0);
  softmax_k<<<NB * SS / 4, 256, 0, stream>>>(big, rinv, 0);
  gemm128<0,0,0,1,0,0,1><<<dim3(DD/128, SS/128, NB), 256, 0, stream>>>(
      big, Vtb, nullptr, nullptr, nullptr, rinv,
      (void*)att, nullptr, nullptr,
      SS, SS, SS, DD, 0.f,
      (long long)SS * SS, (long long)DD * SS, (long long)SS * DD, SS);

  // MLP full-M via the proven gemm128
  gemm128<1,1,0,0,0,0,0><<<dim3(DFFN/128, MTOT/128), 256, 0, stream>>>(
      att, W1b, b1, nullptr, nullptr, nullptr,
      (void*)h, nullptr, nullptr,
      DD, DD, DD, DFFN, 0.f, 0, 0, 0, 0);
  gemm128<1,0,0,0,1,0,0><<<dim3(DD/128, MTOT/128), 256, 0, stream>>>(
      h, W2b, b2, nullptr, nullptr, nullptr,
      (void*)d_out, nullptr, nullptr,
      DFFN, DFFN, DFFN, DD, 0.f, 0, 0, 0, 0);
}

// Round 17
// 677.452 us; speedup vs baseline: 1.0531x; 1.0127x over previous
//
#include <hip/hip_runtime.h>
#include <hip/hip_bf16.h>

#define NB   8
#define SS   2048
#define DD   1024
#define DFFN 4096
#define MTOT (NB*SS)   // 16384

typedef unsigned short u16;
typedef __attribute__((ext_vector_type(4))) float f32x4;
typedef __attribute__((ext_vector_type(8))) short bf16x8;
typedef __attribute__((ext_vector_type(4))) int i32x4;
typedef __attribute__((ext_vector_type(4))) unsigned short u16x4;
typedef __attribute__((ext_vector_type(8))) unsigned short u16x8;

__device__ __forceinline__ u16 f2bf(float f) {
  union { float f; unsigned u; } c; c.f = f;
  unsigned r = c.u + 0x7FFFu + ((c.u >> 16) & 1u);
  return (u16)(r >> 16);
}

__device__ __forceinline__ void gload16(const void* g, void* l) {
  __builtin_amdgcn_global_load_lds(
      (const __attribute__((address_space(1))) void*)(unsigned long long)g,
      (__attribute__((address_space(3))) void*)(unsigned)(unsigned long long)l,
      16, 0, 0);
}

// opaque ds_read_b128 (manual lgkmcnt/vmcnt accounting)
__device__ __forceinline__ bf16x8 dsr128(unsigned addr) {
  i32x4 r;
  asm volatile("ds_read_b128 %0, %1" : "=v"(r) : "v"(addr));
  return __builtin_bit_cast(bf16x8, r);
}

// ---------------------------------------------------------------------------
// 128x128 GEMM-BT: 4 waves (2x2), per-wave 64x64, BK=32. R17: 3-buffer LDS
// ring (48KB), stage t+2 each step, counted vmcnt(4) at the step boundary
// (tile t+1 landed, t+2's 4 loads stay in flight) -> 2-step latency slack
// covers HBM-miss (~900cy). Retest of R6's structure now that the supertile
// block-order (R16) keeps per-XCD B-panels L2-resident (FETCH 322->151MB).
// Swizzled staging, LDS-staged epilogue, bijective XCD swizzle + supertile.
// OUTMODE: 0=bf16, 1=f32, 2=f16, 3=QKV fused (Q,K bf16 rows + V transposed).
// ---------------------------------------------------------------------------
template<int EBIAS, int EGELU, int ESCALE, int EROWSCALE, int OUTMODE, int CSKIP, int CK>
__global__ __launch_bounds__(256, 4)
void gemm128(const u16* __restrict__ A, const u16* __restrict__ B,
             const float* __restrict__ bias0, const float* __restrict__ bias1,
             const float* __restrict__ bias2, const float* __restrict__ rowscale,
             void* __restrict__ C0, void* __restrict__ C1, void* __restrict__ C2,
             int K, int lda, int ldb, int ldc, float scale,
             long long sA, long long sB, long long sC, int sRS)
{
  __shared__ __align__(1024) u16 smem[24576];   // 48 KB (3-ring; epilogue reuse)

  const int gx = gridDim.x, gy = gridDim.y;
  const int nwg = gx * gy;
  const int orig = blockIdx.y * gx + blockIdx.x;
  const int q = nwg >> 3, r = nwg & 7;
  const int xcd = orig & 7, pos0 = orig >> 3;
  const int wg = (xcd < r ? xcd * (q + 1) : r * (q + 1) + (xcd - r) * q) + pos0;
  int bx, by;
  if ((gx & 3) == 0) {               // supertile: 4-col stripes (bijective)
    const int rr = wg % (gy << 2);
    bx = (wg / (gy << 2)) * 4 + (rr & 3);
    by = rr >> 2;
  } else {
    bx = wg % gx; by = wg / gx;
  }
  const int row0 = by * 128, col0 = bx * 128;
  if (CSKIP && col0 > row0 + 127) return;

  const int z = blockIdx.z;
  A += (size_t)z * sA;
  B += (size_t)z * sB;

  int nkt = K >> 5;
  if (CK) { int lim = (row0 + 128) >> 5; if (lim < nkt) nkt = lim; }
  // all instantiations have nkt >= 4

  const int tid  = threadIdx.x;
  const int wid  = tid >> 6;
  const int lane = tid & 63;
  const int wr = wid >> 1, wc = wid & 1;

  const int srow = wid * 16 + (lane >> 2);
  const int sunit = (lane & 3) ^ ((lane >> 3) & 3);
  const char* gA = (const char*)A + ((size_t)(row0 + srow) * lda + sunit * 8) * 2;
  const char* gB = (const char*)B + ((size_t)(col0 + srow) * ldb + sunit * 8) * 2;
  const size_t ldab = (size_t)64 * lda * 2;
  const size_t ldbb = (size_t)64 * ldb * 2;

  // stage K-step t2 into ring slot at byte offset bo (0/16384/32768)
  #define STG(t2, bo) { char* lb = (char*)smem + (bo); size_t kb = (size_t)(t2) * 64; \
      gload16(gA + kb,        lb + wid * 1024);                                       \
      gload16(gA + kb + ldab, lb + 4096 + wid * 1024);                                \
      gload16(gB + kb,        lb + 8192 + wid * 1024);                                \
      gload16(gB + kb + ldbb, lb + 8192 + 4096 + wid * 1024); }

  const int fr = lane & 15;
  const int ks16 = ((lane >> 4) & 3) * 16;
  const int xm = ((lane >> 1) & 3) << 4;
  const unsigned sbase = (unsigned)(unsigned long long)(void*)smem;

  f32x4 acc[4][4] = {};

  // prologue: stage tiles 0 (slot0) and 1 (slot1); vmcnt(4) -> tile 0 landed
  STG(0, 0); STG(1, 16384);
  asm volatile("s_waitcnt vmcnt(4)");
  asm volatile("s_barrier" ::: "memory");

  unsigned cbo = 0, sbo = 32768;   // compute / stage ring offsets

  #define KSTEP_BODY(WAITN)                                                    \
    bf16x8 af[4], bf[4];                                                       \
    _Pragma("unroll") for (int m = 0; m < 4; ++m)                              \
      af[m] = dsr128(sbase + cbo + (((wr * 64 + m * 16 + fr) * 64 + ks16) ^ xm)); \
    _Pragma("unroll") for (int n = 0; n < 4; ++n)                              \
      bf[n] = dsr128(sbase + cbo + ((8192 + (wc * 64 + n * 16 + fr) * 64 + ks16) ^ xm)); \
    asm volatile("s_waitcnt lgkmcnt(0)");                                      \
    __builtin_amdgcn_sched_barrier(0);                                         \
    __builtin_amdgcn_s_setprio(1);                                             \
    _Pragma("unroll") for (int m = 0; m < 4; ++m)                              \
      _Pragma("unroll") for (int n = 0; n < 4; ++n)                            \
        acc[m][n] = __builtin_amdgcn_mfma_f32_16x16x32_bf16(af[m], bf[n], acc[m][n], 0, 0, 0); \
    __builtin_amdgcn_s_setprio(0);                                             \
    asm volatile("s_waitcnt vmcnt(" #WAITN ")");                               \
    asm volatile("s_barrier" ::: "memory");                                    \
    cbo += 16384; if (cbo == 49152) cbo = 0;                                   \
    sbo += 16384; if (sbo == 49152) sbo = 0;

  // main loop: stage t+2; vmcnt(4) -> tile t+1 landed, t+2's 4 in flight
  for (int t = 0; t < nkt - 2; ++t) {
    STG(t + 2, sbo);
    KSTEP_BODY(4)
  }
  // tail: last 2 steps, nothing newer staged -> vmcnt(0)
  { KSTEP_BODY(0) }
  { KSTEP_BODY(0) }
  #undef KSTEP_BODY
  #undef STG

  // ---- epilogue via LDS ----
  char* sm = (char*)smem;
  const int r4 = (lane >> 4) * 4;
  const int sel  = (OUTMODE == 3) ? (col0 >> 10) : 0;
  const int oc0  = (OUTMODE == 3) ? (col0 & 1023) : col0;
  const float* bias = (OUTMODE == 3) ? (sel == 0 ? bias0 : sel == 1 ? bias1 : bias2)
                                     : bias0;

  if (OUTMODE == 1) {
#pragma unroll
    for (int p = 0; p < 2; ++p) {
      if (wc == p) {
#pragma unroll
        for (int n = 0; n < 4; ++n) {
          const int col = oc0 + wc * 64 + n * 16 + fr;
          const int pb = (n * 16 + fr) * 4;
          float bia = EBIAS ? bias[col] : 0.0f;
#pragma unroll
          for (int m = 0; m < 4; ++m) {
#pragma unroll
            for (int j = 0; j < 4; ++j) {
              const int line = wr * 64 + m * 16 + r4 + j;
              float xv = acc[m][n][j];
              if (EBIAS)     xv += bia;
              if (ESCALE)    xv *= scale;
              if (EROWSCALE) xv *= rowscale[z * sRS + row0 + line];
              if (EGELU)     xv = 0.5f * xv * (1.0f + erff(xv * 0.70710678118f));
              *(float*)(sm + ((line * 256 + pb) ^ ((line & 7) << 4))) = xv;
            }
          }
        }
      }
      __syncthreads();
      float* Cb = (float*)C0 + (size_t)z * sC;
#pragma unroll
      for (int i = 0; i < 8; ++i) {
        const int o = i * 4096 + tid * 16;
        const int line = o >> 8, ps = o & 255;
        f32x4 v = *(const f32x4*)(sm + ((line * 256 + ps) ^ ((line & 7) << 4)));
        *(f32x4*)((char*)(Cb + (size_t)(row0 + line) * ldc + oc0 + p * 64) + ps) = v;
      }
      __syncthreads();
    }
  } else if (OUTMODE == 3 && sel == 2) {
#pragma unroll
    for (int n = 0; n < 4; ++n) {
      const int line = wc * 64 + n * 16 + fr;
      float bia = EBIAS ? bias[oc0 + line] : 0.0f;
#pragma unroll
      for (int m = 0; m < 4; ++m) {
        const int rb = wr * 64 + m * 16 + r4;
        u16x4 pk;
#pragma unroll
        for (int j = 0; j < 4; ++j) pk[j] = f2bf(acc[m][n][j] + bia);
        *(u16x4*)(sm + ((line * 256 + rb * 2) ^ ((line & 7) << 4))) = pk;
      }
    }
    __syncthreads();
    u16* Cb = (u16*)C2 + (size_t)(row0 >> 11) * (DD * SS) + (row0 & (SS - 1));
#pragma unroll
    for (int i = 0; i < 8; ++i) {
      const int o = i * 4096 + tid * 16;
      const int line = o >> 8, ps = o & 255;
      f32x4 v = *(const f32x4*)(sm + ((line * 256 + ps) ^ ((line & 7) << 4)));
      *(f32x4*)((char*)(Cb + (size_t)(oc0 + line) * SS) + ps) = v;
    }
  } else {
#pragma unroll
    for (int n = 0; n < 4; ++n) {
      const int col = oc0 + wc * 64 + n * 16 + fr;
      const int pc = (wc * 64 + n * 16 + fr) * 2;
      float bia = EBIAS ? bias[col] : 0.0f;
#pragma unroll
      for (int m = 0; m < 4; ++m) {
#pragma unroll
        for (int j = 0; j < 4; ++j) {
          const int line = wr * 64 + m * 16 + r4 + j;
          float xv = acc[m][n][j];
          if (EBIAS)     xv += bia;
          if (ESCALE)    xv *= scale;
          if (EROWSCALE) xv *= rowscale[z * sRS + row0 + line];
          if (EGELU)     xv = 0.5f * xv * (1.0f + erff(xv * 0.70710678118f));
          u16 u;
          if (OUTMODE == 2) { union { u16 s; _Float16 h; } cu; cu.h = (_Float16)xv; u = cu.s; }
          else u = f2bf(xv);
          *(u16*)(sm + ((line * 256 + pc) ^ ((line & 7) << 4))) = u;
        }
      }
    }
    __syncthreads();
    u16* Cb = (u16*)(OUTMODE == 3 ? (sel ? C1 : C0) : C0) + (size_t)z * sC + oc0;
#pragma unroll
    for (int i = 0; i < 8; ++i) {
      const int o = i * 4096 + tid * 16;
      const int line = o >> 8, ps = o & 255;
      f32x4 v = *(const f32x4*)(sm + ((line * 256 + ps) ^ ((line & 7) << 4)));
      *(f32x4*)((char*)(Cb + (size_t)(row0 + line) * ldc) + ps) = v;
    }
  }
}

// single fused f32->bf16 convert: x -> out_x, weights -> out_w (contiguous)
__global__ __launch_bounds__(256) void cvt_all_k(
    const float* __restrict__ x,  const float* __restrict__ wq,
    const float* __restrict__ wk, const float* __restrict__ wv,
    const float* __restrict__ w1, const float* __restrict__ w2,
    u16* __restrict__ out_x, u16* __restrict__ out_w)
{
  const int i = blockIdx.x * 256 + threadIdx.x;   // float4 index
  const float* src; int off; u16* dst; int dofs;
  if (i < 4194304)      { src = x;  off = i;           dst = out_x; dofs = i; }
  else if (i < 4456448) { src = wq; off = i - 4194304; dst = out_w; dofs = i - 4194304; }
  else if (i < 4718592) { src = wk; off = i - 4456448; dst = out_w; dofs = i - 4194304; }
  else if (i < 4980736) { src = wv; off = i - 4718592; dst = out_w; dofs = i - 4194304; }
  else if (i < 6029312) { src = w1; off = i - 4980736; dst = out_w; dofs = i - 4194304; }
  else                  { src = w2; off = i - 6029312; dst = out_w; dofs = i - 4194304; }
  float4 v = ((const float4*)src)[off];
  u16x4 o;
  o.x = f2bf(v.x); o.y = f2bf(v.y); o.z = f2bf(v.z); o.w = f2bf(v.w);
  ((u16x4*)dst)[dofs] = o;
}

// batched row softmax over f16 scores -> unnormalized bf16 P + 1/sum
__global__ __launch_bounds__(256) void softmax_k(u16* __restrict__ sc, float* __restrict__ rinv, int rows0) {
  const int widx = blockIdx.x * 4 + (threadIdx.x >> 6);
  const int lane = threadIdx.x & 63;
  u16* row = sc + (size_t)widx * SS;
  const int L = (widx & (SS - 1)) + 1;
  float mx = -1e30f;
  for (int k = 0; k < 4; ++k) {
    const int j0 = k * 512 + lane * 8;
    if (j0 < L) {
      u16x8 v = *(const u16x8*)(row + j0);
      int lim = L - j0; if (lim > 8) lim = 8;
#pragma unroll
      for (int e = 0; e < 8; ++e) {
        if (e < lim) { union { u16 u; _Float16 h; } c; c.u = v[e]; mx = fmaxf(mx, (float)c.h); }
      }
    }
  }
#pragma unroll
  for (int o = 32; o >= 1; o >>= 1) mx = fmaxf(mx, __shfl_xor(mx, o));
  float sacc = 0.0f;
  for (int k = 0; k < 4; ++k) {
    const int j0 = k * 512 + lane * 8;
    u16x8 v = *(const u16x8*)(row + j0);
    u16x8 w;
#pragma unroll
    for (int e = 0; e < 8; ++e) {
      const int j = j0 + e;
      float ev = 0.0f;
      if (j < L) { union { u16 u; _Float16 h; } c; c.u = v[e]; ev = __expf((float)c.h - mx); sacc += ev; }
      w[e] = f2bf(ev);
    }
    *(u16x8*)(row + j0) = w;
  }
#pragma unroll
  for (int o = 32; o >= 1; o >>= 1) sacc += __shfl_xor(sacc, o);
  if (lane == 0) rinv[rows0 + widx] = 1.0f / sacc;
}

extern "C" void kernel_launch(void* const* d_in, const int* in_sizes, int n_in,
                              void* d_out, int out_size, void* d_ws, size_t ws_size,
                              hipStream_t stream) {
  const float* x  = (const float*)d_in[0];
  const float* Wq = (const float*)d_in[1];
  const float* bq = (const float*)d_in[2];
  const float* Wk = (const float*)d_in[3];
  const float* bk = (const float*)d_in[4];
  const float* Wv = (const float*)d_in[5];
  const float* bv = (const float*)d_in[6];
  const float* W1 = (const float*)d_in[7];
  const float* b1 = (const float*)d_in[8];
  const float* W2 = (const float*)d_in[9];
  const float* b2 = (const float*)d_in[10];

  char* ws = (char*)d_ws;
  u16*  Qb   = (u16*)(ws);                          // 32 MB; att overwrites
  u16*  Kb   = (u16*)(ws + 33554432);               // 32 MB; h overwrites
  u16*  Vtb  = (u16*)(ws + 67108864);               // 32 MB
  u16*  big  = (u16*)(ws + 100663296);              // scores/P 64 MB; xb first
  float* rinv = (float*)(ws + 167772160);           // 64 KB
  u16*  Wcat = (u16*)(ws + 167772160 + 65536);      // 6 MB
  u16*  W1b  = Wcat + 3 * DD * DD;                  // 8 MB
  u16*  W2b  = W1b + DFFN * DD;                     // 8 MB
  u16*  xb   = big;
  u16*  att  = Qb;
  u16*  h    = Kb;                                  // 128 MB over Kb|Vtb|big

  cvt_all_k<<<27648, 256, 0, stream>>>(x, Wq, Wk, Wv, W1, W2, xb, Wcat);

  // fused QKV projection: N = 3072, grid 24 x 128
  gemm128<1,0,0,0,3,0,0><<<dim3(3 * DD / 128, MTOT / 128), 256, 0, stream>>>(
      xb, Wcat, bq, bk, bv, nullptr, (void*)Qb, (void*)Kb, (void*)Vtb,
      DD, DD, DD, DD, 0.f, 0, 0, 0, 0);

  // attention, all batches
  gemm128<0,0,1,0,2,1,0><<<dim3(SS/128, SS/128, NB), 256, 0, stream>>>(
      Qb, Kb, nullptr, nullptr, nullptr, nullptr, (void*)big, nullptr, nullptr,
      DD, DD, DD, SS, 0.03125f,
      (long long)SS * DD, (long long)SS * DD, (long long)SS * SS, 0);
  softmax_k<<<NB * SS / 4, 256, 0, stream>>>(big, rinv, 0);
  gemm128<0,0,0,1,0,0,1><<<dim3(DD/128, SS/128, NB), 256, 0, stream>>>(
      big, Vtb, nullptr, nullptr, nullptr, rinv,
      (void*)att, nullptr, nullptr,
      SS, SS, SS, DD, 0.f,
      (long long)SS * SS, (long long)DD * SS, (long long)SS * DD, SS);

  // MLP full-M
  gemm128<1,1,0,0,0,0,0><<<dim3(DFFN/128, MTOT/128), 256, 0, stream>>>(
      att, W1b, b1, nullptr, nullptr, nullptr,
      (void*)h, nullptr, nullptr,
      DD, DD, DD, DFFN, 0.f, 0, 0, 0, 0);
  gemm128<1,0,0,0,1,0,0><<<dim3(DD/128, MTOT/128), 256, 0, stream>>>(
      h, W2b, b2, nullptr, nullptr, nullptr,
      (void*)d_out, nullptr, nullptr,
      DFFN, DFFN, DFFN, DD, 0.f, 0, 0, 0, 0);
}